// Round 6
// baseline (376.861 us; speedup 1.0000x reference)
//
#include <hip/hip_runtime.h>
#include <math.h>

#define N_NODES 10000
#define N_EDGES 320000
#define N_AUG   (N_EDGES + N_NODES)
#define HID     256

// ---------------- degree + edge_attr segment sum ----------------
__global__ void k_deg(const int* __restrict__ dst, const float* __restrict__ ea,
                      int* __restrict__ deg, float* __restrict__ asum) {
  int e = blockIdx.x * blockDim.x + threadIdx.x;
  if (e < N_EDGES) {
    int d = dst[e];
    atomicAdd(&deg[d], 1);
    atomicAdd(&asum[d], ea[e]);
  }
}

// ------- exclusive scan of (deg+1) over 10000 nodes (parallel), + loop_attr --
__global__ void __launch_bounds__(256) k_scan(
    const int* __restrict__ deg, const float* __restrict__ asum,
    int* __restrict__ offs, float* __restrict__ lattr) {
  __shared__ int wsum[4];
  int t = threadIdx.x;
  int base = t * 40;
  int s = 0;
  for (int i = 0; i < 40; i++) {
    int n = base + i;
    if (n < N_NODES) s += deg[n] + 1;
  }
  int v = s;
  #pragma unroll
  for (int d = 1; d < 64; d <<= 1) {
    int u = __shfl_up(v, d);
    if ((t & 63) >= d) v += u;
  }
  if ((t & 63) == 63) wsum[t >> 6] = v;
  __syncthreads();
  int wb = 0;
  for (int i = 0; i < (t >> 6); i++) wb += wsum[i];
  int run = wb + v - s;
  for (int i = 0; i < 40; i++) {
    int n = base + i;
    if (n < N_NODES) {
      offs[n] = run;
      int d = deg[n];
      run += d + 1;
      lattr[n] = asum[n] / (float)max(d, 1);
    }
  }
  if (t == 255) offs[N_NODES] = wb + v;
}

// ------- scatter edges (incl. self loops) into CSR by dst, packed (src,ea) --
__global__ void k_scatter(const int* __restrict__ src, const int* __restrict__ dst,
                          const float* __restrict__ ea, const float* __restrict__ lattr,
                          const int* __restrict__ offs, int* __restrict__ cursor,
                          int2* __restrict__ cpk) {
  int e = blockIdx.x * blockDim.x + threadIdx.x;
  if (e >= N_AUG) return;
  int s, d; float a;
  if (e < N_EDGES) { s = src[e]; d = dst[e]; a = ea[e]; }
  else             { s = e - N_EDGES; d = s; a = lattr[s]; }
  int pos = offs[d] + atomicAdd(&cursor[d], 1);
  cpk[pos] = make_int2(s, __float_as_int(a));
}

// ---------------- conv1: fully fused, vector broadcast loads, 4-edge unroll -
#define C1_EDGE(xs, av, l0, l1, l2, l3, p)                                              \
  {                                                                                     \
    l0 = fmaf(xs.x,wl0.x, fmaf(xs.y,wl1.x, fmaf(xs.z,wl2.x, fmaf(xs.w,wl3.x, blv.x)))); \
    l1 = fmaf(xs.x,wl0.y, fmaf(xs.y,wl1.y, fmaf(xs.z,wl2.y, fmaf(xs.w,wl3.y, blv.y)))); \
    l2 = fmaf(xs.x,wl0.z, fmaf(xs.y,wl1.z, fmaf(xs.z,wl2.z, fmaf(xs.w,wl3.z, blv.z)))); \
    l3 = fmaf(xs.x,wl0.w, fmaf(xs.y,wl1.w, fmaf(xs.z,wl2.w, fmaf(xs.w,wl3.w, blv.w)))); \
    float m0 = l0 + fmaf(av, we.x, r4.x); m0 = fmaxf(m0, 0.2f*m0);                      \
    float m1 = l1 + fmaf(av, we.y, r4.y); m1 = fmaxf(m1, 0.2f*m1);                      \
    float m2 = l2 + fmaf(av, we.z, r4.z); m2 = fmaxf(m2, 0.2f*m2);                      \
    float m3 = l3 + fmaf(av, we.w, r4.w); m3 = fmaxf(m3, 0.2f*m3);                      \
    p = m0*at.x + m1*at.y + m2*at.z + m3*at.w;                                          \
  }

__global__ void __launch_bounds__(256) k_conv1(
    const float* __restrict__ x,
    const float* __restrict__ Wl, const float* __restrict__ bl,
    const float* __restrict__ Wr, const float* __restrict__ br,
    const float* __restrict__ We, const float* __restrict__ att,
    const int* __restrict__ offs, const int2* __restrict__ cpk,
    const float* __restrict__ bias, const float* __restrict__ g,
    const float* __restrict__ be, float* __restrict__ hout) {
  int t = threadIdx.x;
  int n = blockIdx.x * 4 + (t >> 6);
  int c = 4 * (t & 63);

  float4 wl0 = *(const float4*)&Wl[0*HID + c];
  float4 wl1 = *(const float4*)&Wl[1*HID + c];
  float4 wl2 = *(const float4*)&Wl[2*HID + c];
  float4 wl3 = *(const float4*)&Wl[3*HID + c];
  float4 blv = *(const float4*)&bl[c];
  float4 we  = *(const float4*)&We[c];
  float4 at  = *(const float4*)&att[c];

  float4 xn = *(const float4*)&x[n*4];
  float4 r4;
  {
    float4 wr0 = *(const float4*)&Wr[0*HID + c];
    float4 wr1 = *(const float4*)&Wr[1*HID + c];
    float4 wr2 = *(const float4*)&Wr[2*HID + c];
    float4 wr3 = *(const float4*)&Wr[3*HID + c];
    float4 brv = *(const float4*)&br[c];
    r4.x = fmaf(xn.x,wr0.x, fmaf(xn.y,wr1.x, fmaf(xn.z,wr2.x, fmaf(xn.w,wr3.x, brv.x))));
    r4.y = fmaf(xn.x,wr0.y, fmaf(xn.y,wr1.y, fmaf(xn.z,wr2.y, fmaf(xn.w,wr3.y, brv.y))));
    r4.z = fmaf(xn.x,wr0.z, fmaf(xn.y,wr1.z, fmaf(xn.z,wr2.z, fmaf(xn.w,wr3.z, brv.z))));
    r4.w = fmaf(xn.x,wr0.w, fmaf(xn.y,wr1.w, fmaf(xn.z,wr2.w, fmaf(xn.w,wr3.w, brv.w))));
  }

  int js = __builtin_amdgcn_readfirstlane(offs[n]);
  int je = __builtin_amdgcn_readfirstlane(offs[n+1]);

  float D = 0.f, a0 = 0.f, a1 = 0.f, a2 = 0.f, a3 = 0.f;

  int j = js;
  for (; j + 3 < je; j += 4) {
    int2 eA = cpk[j], eB = cpk[j+1], eC = cpk[j+2], eD = cpk[j+3];
    float4 xA = *(const float4*)&x[eA.x*4];   // broadcast vector load
    float4 xB = *(const float4*)&x[eB.x*4];
    float4 xC = *(const float4*)&x[eC.x*4];
    float4 xD = *(const float4*)&x[eD.x*4];
    float avA = __int_as_float(eA.y), avB = __int_as_float(eB.y);
    float avC = __int_as_float(eC.y), avD = __int_as_float(eD.y);

    float lA0,lA1,lA2,lA3,pA, lB0,lB1,lB2,lB3,pB;
    float lC0,lC1,lC2,lC3,pC, lD0,lD1,lD2,lD3,pD;
    C1_EDGE(xA, avA, lA0,lA1,lA2,lA3, pA);
    C1_EDGE(xB, avB, lB0,lB1,lB2,lB3, pB);
    C1_EDGE(xC, avC, lC0,lC1,lC2,lC3, pC);
    C1_EDGE(xD, avD, lD0,lD1,lD2,lD3, pD);

    #pragma unroll
    for (int msk = 1; msk < 16; msk <<= 1) {
      pA += __shfl_xor(pA, msk);
      pB += __shfl_xor(pB, msk);
      pC += __shfl_xor(pC, msk);
      pD += __shfl_xor(pD, msk);
    }
    float eAx = expf(pA), eBx = expf(pB), eCx = expf(pC), eDx = expf(pD);
    D += (eAx + eBx) + (eCx + eDx);
    a0 = fmaf(eDx, lD0, fmaf(eCx, lC0, fmaf(eBx, lB0, fmaf(eAx, lA0, a0))));
    a1 = fmaf(eDx, lD1, fmaf(eCx, lC1, fmaf(eBx, lB1, fmaf(eAx, lA1, a1))));
    a2 = fmaf(eDx, lD2, fmaf(eCx, lC2, fmaf(eBx, lB2, fmaf(eAx, lA2, a2))));
    a3 = fmaf(eDx, lD3, fmaf(eCx, lC3, fmaf(eBx, lB3, fmaf(eAx, lA3, a3))));
  }
  for (; j < je; j++) {
    int2 eA = cpk[j];
    float4 xA = *(const float4*)&x[eA.x*4];
    float avA = __int_as_float(eA.y);
    float lA0,lA1,lA2,lA3,pA;
    C1_EDGE(xA, avA, lA0,lA1,lA2,lA3, pA);
    #pragma unroll
    for (int msk = 1; msk < 16; msk <<= 1) pA += __shfl_xor(pA, msk);
    float eAx = expf(pA);
    D += eAx;
    a0 = fmaf(eAx, lA0, a0);
    a1 = fmaf(eAx, lA1, a1);
    a2 = fmaf(eAx, lA2, a2);
    a3 = fmaf(eAx, lA3, a3);
  }

  float inv = 1.f / D;
  float4 b4 = *(const float4*)&bias[c];
  float o0 = fmaf(a0, inv, b4.x);
  float o1 = fmaf(a1, inv, b4.y);
  float o2 = fmaf(a2, inv, b4.z);
  float o3 = fmaf(a3, inv, b4.w);

  float s = o0 + o1 + o2 + o3;
  #pragma unroll
  for (int msk = 1; msk < 64; msk <<= 1) s += __shfl_xor(s, msk);
  float mu = s * (1.f / 256.f);
  float d0 = o0 - mu, d1 = o1 - mu, d2 = o2 - mu, d3 = o3 - mu;
  float sq = d0*d0 + d1*d1 + d2*d2 + d3*d3;
  #pragma unroll
  for (int msk = 1; msk < 64; msk <<= 1) sq += __shfl_xor(sq, msk);
  float rstd = rsqrtf(sq * (1.f / 256.f) + 1e-5f);
  float4 g4  = *(const float4*)&g[c];
  float4 be4 = *(const float4*)&be[c];
  float4 o;
  o.x = fmaxf(fmaf(d0 * rstd, g4.x, be4.x), 0.f);
  o.y = fmaxf(fmaf(d1 * rstd, g4.y, be4.y), 0.f);
  o.z = fmaxf(fmaf(d2 * rstd, g4.z, be4.z), 0.f);
  o.w = fmaxf(fmaf(d3 * rstd, g4.w, be4.w), 0.f);
  *(float4*)&hout[n*HID + c] = o;
}

// ---------------- conv2: gather-based, no online max, 8-edge unroll ---------
#define C2_EDGE(xs, av, p)                                        \
  {                                                               \
    float m0 = xs.x + fmaf(av, we.x, r4.x); m0 = fmaxf(m0, 0.2f*m0); \
    float m1 = xs.y + fmaf(av, we.y, r4.y); m1 = fmaxf(m1, 0.2f*m1); \
    float m2 = xs.z + fmaf(av, we.z, r4.z); m2 = fmaxf(m2, 0.2f*m2); \
    float m3 = xs.w + fmaf(av, we.w, r4.w); m3 = fmaxf(m3, 0.2f*m3); \
    p = m0*at.x + m1*at.y + m2*at.z + m3*at.w;                    \
  }

__global__ void __launch_bounds__(256) k_conv2(
    const float* __restrict__ xl, const float* __restrict__ xr,
    const int* __restrict__ offs, const int2* __restrict__ cpk,
    const float* __restrict__ We, const float* __restrict__ att,
    const float* __restrict__ bias, const float* __restrict__ g,
    const float* __restrict__ be, float* __restrict__ hout) {
  int t = threadIdx.x;
  int n = blockIdx.x * 4 + (t >> 6);
  int c = 4 * (t & 63);
  float4 r4 = *(const float4*)&xr[n*HID + c];
  float4 we = *(const float4*)&We[c];
  float4 at = *(const float4*)&att[c];
  int js = __builtin_amdgcn_readfirstlane(offs[n]);
  int je = __builtin_amdgcn_readfirstlane(offs[n+1]);

  float D = 0.f, a0 = 0.f, a1 = 0.f, a2 = 0.f, a3 = 0.f;

  int j = js;
  for (; j + 7 < je; j += 8) {
    int2 e0 = cpk[j],   e1 = cpk[j+1], e2 = cpk[j+2], e3 = cpk[j+3];
    int2 e4 = cpk[j+4], e5 = cpk[j+5], e6 = cpk[j+6], e7 = cpk[j+7];
    float4 xs0 = *(const float4*)&xl[e0.x*HID + c];
    float4 xs1 = *(const float4*)&xl[e1.x*HID + c];
    float4 xs2 = *(const float4*)&xl[e2.x*HID + c];
    float4 xs3 = *(const float4*)&xl[e3.x*HID + c];
    float4 xs4 = *(const float4*)&xl[e4.x*HID + c];
    float4 xs5 = *(const float4*)&xl[e5.x*HID + c];
    float4 xs6 = *(const float4*)&xl[e6.x*HID + c];
    float4 xs7 = *(const float4*)&xl[e7.x*HID + c];
    float av0 = __int_as_float(e0.y), av1 = __int_as_float(e1.y);
    float av2 = __int_as_float(e2.y), av3 = __int_as_float(e3.y);
    float av4 = __int_as_float(e4.y), av5 = __int_as_float(e5.y);
    float av6 = __int_as_float(e6.y), av7 = __int_as_float(e7.y);

    float p0,p1,p2,p3,p4,p5,p6,p7;
    C2_EDGE(xs0, av0, p0); C2_EDGE(xs1, av1, p1);
    C2_EDGE(xs2, av2, p2); C2_EDGE(xs3, av3, p3);
    C2_EDGE(xs4, av4, p4); C2_EDGE(xs5, av5, p5);
    C2_EDGE(xs6, av6, p6); C2_EDGE(xs7, av7, p7);
    #pragma unroll
    for (int msk = 1; msk < 64; msk <<= 1) {
      p0 += __shfl_xor(p0, msk); p1 += __shfl_xor(p1, msk);
      p2 += __shfl_xor(p2, msk); p3 += __shfl_xor(p3, msk);
      p4 += __shfl_xor(p4, msk); p5 += __shfl_xor(p5, msk);
      p6 += __shfl_xor(p6, msk); p7 += __shfl_xor(p7, msk);
    }
    float x0 = expf(p0), x1 = expf(p1), x2 = expf(p2), x3 = expf(p3);
    float x4 = expf(p4), x5 = expf(p5), x6 = expf(p6), x7 = expf(p7);
    D += ((x0 + x1) + (x2 + x3)) + ((x4 + x5) + (x6 + x7));
    a0 = fmaf(x3, xs3.x, fmaf(x2, xs2.x, fmaf(x1, xs1.x, fmaf(x0, xs0.x, a0))));
    a0 = fmaf(x7, xs7.x, fmaf(x6, xs6.x, fmaf(x5, xs5.x, fmaf(x4, xs4.x, a0))));
    a1 = fmaf(x3, xs3.y, fmaf(x2, xs2.y, fmaf(x1, xs1.y, fmaf(x0, xs0.y, a1))));
    a1 = fmaf(x7, xs7.y, fmaf(x6, xs6.y, fmaf(x5, xs5.y, fmaf(x4, xs4.y, a1))));
    a2 = fmaf(x3, xs3.z, fmaf(x2, xs2.z, fmaf(x1, xs1.z, fmaf(x0, xs0.z, a2))));
    a2 = fmaf(x7, xs7.z, fmaf(x6, xs6.z, fmaf(x5, xs5.z, fmaf(x4, xs4.z, a2))));
    a3 = fmaf(x3, xs3.w, fmaf(x2, xs2.w, fmaf(x1, xs1.w, fmaf(x0, xs0.w, a3))));
    a3 = fmaf(x7, xs7.w, fmaf(x6, xs6.w, fmaf(x5, xs5.w, fmaf(x4, xs4.w, a3))));
  }
  for (; j < je; j++) {
    int2 e0 = cpk[j];
    float av0 = __int_as_float(e0.y);
    float4 xs0 = *(const float4*)&xl[e0.x*HID + c];
    float p0;
    C2_EDGE(xs0, av0, p0);
    #pragma unroll
    for (int msk = 1; msk < 64; msk <<= 1) p0 += __shfl_xor(p0, msk);
    float x0 = expf(p0);
    D += x0;
    a0 = fmaf(x0, xs0.x, a0);
    a1 = fmaf(x0, xs0.y, a1);
    a2 = fmaf(x0, xs0.z, a2);
    a3 = fmaf(x0, xs0.w, a3);
  }

  float inv = 1.f / D;
  float4 b4 = *(const float4*)&bias[c];
  float o0 = fmaf(a0, inv, b4.x);
  float o1 = fmaf(a1, inv, b4.y);
  float o2 = fmaf(a2, inv, b4.z);
  float o3 = fmaf(a3, inv, b4.w);

  float s = o0 + o1 + o2 + o3;
  #pragma unroll
  for (int msk = 1; msk < 64; msk <<= 1) s += __shfl_xor(s, msk);
  float mu = s * (1.f / 256.f);
  float d0 = o0 - mu, d1 = o1 - mu, d2 = o2 - mu, d3 = o3 - mu;
  float sq = d0*d0 + d1*d1 + d2*d2 + d3*d3;
  #pragma unroll
  for (int msk = 1; msk < 64; msk <<= 1) sq += __shfl_xor(sq, msk);
  float rstd = rsqrtf(sq * (1.f / 256.f) + 1e-5f);
  float4 g4  = *(const float4*)&g[c];
  float4 be4 = *(const float4*)&be[c];
  float4 o;
  o.x = fmaxf(fmaf(d0 * rstd, g4.x, be4.x), 0.f);
  o.y = fmaxf(fmaf(d1 * rstd, g4.y, be4.y), 0.f);
  o.z = fmaxf(fmaf(d2 * rstd, g4.z, be4.z), 0.f);
  o.w = fmaxf(fmaf(d3 * rstd, g4.w, be4.w), 0.f);
  *(float4*)&hout[n*HID + c] = o;
}

// ---------------- dual GEMM: 128 rows x 64(+64) cols, 8x(4+4)/thread --------
// 256 threads (4 waves), grid 79x4 = 316 blocks = 1264 waves (4.9/CU).
// Per-wave k-step: a 2xb128 (ty in 0..3 -> banks 8ty, conflict-free, 24 cyc),
// w 2xb128 (tx*16B, 2-way=free, 24 cyc) -> LDS 48 vs VALU 128 -> cap 67%.
__global__ void __launch_bounds__(256) k_gemm_dual(
    const float* __restrict__ A,
    const float* __restrict__ W1, const float* __restrict__ b1,
    const float* __restrict__ W2, const float* __restrict__ b2,
    float* __restrict__ O1, float* __restrict__ O2) {
  __shared__ __align__(16) float As[16][132];
  __shared__ __align__(16) float Ws1[16][68];
  __shared__ __align__(16) float Ws2[16][68];
  int t = threadIdx.x;
  int r0 = blockIdx.x * 128;
  int c0 = blockIdx.y * 64;
  int tx = t & 15, ty = t >> 4;     // tx: 4-col group, ty: 8-row group

  float acc1[8][4] = {{0}}, acc2[8][4] = {{0}};

  // staging indices
  int ar  = t >> 1;                 // 0..127 row
  int ak  = (t & 1) * 8;            // k-half 0/8
  int arow = min(r0 + ar, N_NODES - 1);
  int wk  = t >> 4;                 // 0..15
  int wc  = (t & 15) * 4;           // 0..60

  for (int k0 = 0; k0 < HID; k0 += 16) {
    float4 av0 = *(const float4*)&A[arow*HID + k0 + ak];
    float4 av1 = *(const float4*)&A[arow*HID + k0 + ak + 4];
    float4 w1v = *(const float4*)&W1[(k0+wk)*HID + c0 + wc];
    float4 w2v = *(const float4*)&W2[(k0+wk)*HID + c0 + wc];
    __syncthreads();
    As[ak+0][ar] = av0.x; As[ak+1][ar] = av0.y;
    As[ak+2][ar] = av0.z; As[ak+3][ar] = av0.w;
    As[ak+4][ar] = av1.x; As[ak+5][ar] = av1.y;
    As[ak+6][ar] = av1.z; As[ak+7][ar] = av1.w;
    *(float4*)&Ws1[wk][wc] = w1v;
    *(float4*)&Ws2[wk][wc] = w2v;
    __syncthreads();
    #pragma unroll
    for (int k = 0; k < 16; k++) {
      float4 aA = *(const float4*)&As[k][ty*8];
      float4 aB = *(const float4*)&As[k][ty*8 + 4];
      float4 w1 = *(const float4*)&Ws1[k][tx*4];
      float4 w2 = *(const float4*)&Ws2[k][tx*4];
      const float aa[8]  = {aA.x,aA.y,aA.z,aA.w, aB.x,aB.y,aB.z,aB.w};
      const float ww1[4] = {w1.x,w1.y,w1.z,w1.w};
      const float ww2[4] = {w2.x,w2.y,w2.z,w2.w};
      #pragma unroll
      for (int i = 0; i < 8; i++) {
        #pragma unroll
        for (int jj = 0; jj < 4; jj++) {
          acc1[i][jj] = fmaf(aa[i], ww1[jj], acc1[i][jj]);
          acc2[i][jj] = fmaf(aa[i], ww2[jj], acc2[i][jj]);
        }
      }
    }
  }
  int cb = c0 + tx*4;
  float4 b1v = *(const float4*)&b1[cb];
  float4 b2v = *(const float4*)&b2[cb];
  #pragma unroll
  for (int i = 0; i < 8; i++) {
    int r = r0 + ty*8 + i;
    if (r < N_NODES) {
      float4 o1 = {acc1[i][0]+b1v.x, acc1[i][1]+b1v.y, acc1[i][2]+b1v.z, acc1[i][3]+b1v.w};
      float4 o2 = {acc2[i][0]+b2v.x, acc2[i][1]+b2v.y, acc2[i][2]+b2v.z, acc2[i][3]+b2v.w};
      *(float4*)&O1[r*HID + cb] = o1;
      *(float4*)&O2[r*HID + cb] = o2;
    }
  }
}

// ------- fused policy head: 64x128 tile, 8x8/thread, then 128-dot + exp -----
__global__ void __launch_bounds__(128) k_policy(
    const float* __restrict__ h,
    const float* __restrict__ Wp1, const float* __restrict__ bp1,
    const float* __restrict__ Wp2, const float* __restrict__ bp2,
    float* __restrict__ elg, float* __restrict__ tot) {
  __shared__ __align__(16) float As[16][68];
  __shared__ __align__(16) float Ws[16][132];
  __shared__ __align__(16) float hidl[64][132];
  __shared__ float wred[2];
  int t = threadIdx.x;
  int r0 = blockIdx.x * 64;
  int tx = t & 15, ty = t >> 4;

  float acc[8][8] = {{0}};

  int ar  = t >> 1;
  int akh = (t & 1) * 8;
  int arow = min(r0 + ar, N_NODES - 1);
  int wk = t >> 3;
  int wc = (t & 7) * 16;

  for (int k0 = 0; k0 < HID; k0 += 16) {
    const float* Ap = &h[arow*HID + k0 + akh];
    float4 av0 = *(const float4*)&Ap[0];
    float4 av1 = *(const float4*)&Ap[4];
    const float* Wp = &Wp1[(k0+wk)*128 + wc];
    float4 wv0 = *(const float4*)&Wp[0];
    float4 wv1 = *(const float4*)&Wp[4];
    float4 wv2 = *(const float4*)&Wp[8];
    float4 wv3 = *(const float4*)&Wp[12];
    __syncthreads();
    As[akh+0][ar]=av0.x; As[akh+1][ar]=av0.y; As[akh+2][ar]=av0.z; As[akh+3][ar]=av0.w;
    As[akh+4][ar]=av1.x; As[akh+5][ar]=av1.y; As[akh+6][ar]=av1.z; As[akh+7][ar]=av1.w;
    *(float4*)&Ws[wk][wc+ 0] = wv0;
    *(float4*)&Ws[wk][wc+ 4] = wv1;
    *(float4*)&Ws[wk][wc+ 8] = wv2;
    *(float4*)&Ws[wk][wc+12] = wv3;
    __syncthreads();
    #pragma unroll
    for (int k = 0; k < 16; k++) {
      float4 aA = *(const float4*)&As[k][ty*8];
      float4 aB = *(const float4*)&As[k][ty*8+4];
      float4 wA = *(const float4*)&Ws[k][tx*8];
      float4 wB = *(const float4*)&Ws[k][tx*8+4];
      const float aa[8] = {aA.x,aA.y,aA.z,aA.w, aB.x,aB.y,aB.z,aB.w};
      const float ww[8] = {wA.x,wA.y,wA.z,wA.w, wB.x,wB.y,wB.z,wB.w};
      #pragma unroll
      for (int i = 0; i < 8; i++)
        #pragma unroll
        for (int jj = 0; jj < 8; jj++)
          acc[i][jj] = fmaf(aa[i], ww[jj], acc[i][jj]);
    }
  }
  int cbase = tx*8;
  float4 bA = *(const float4*)&bp1[cbase];
  float4 bB = *(const float4*)&bp1[cbase+4];
  const float bb[8] = {bA.x,bA.y,bA.z,bA.w, bB.x,bB.y,bB.z,bB.w};
  #pragma unroll
  for (int i = 0; i < 8; i++) {
    int r = ty*8 + i;
    float4 oA = {fmaxf(acc[i][0]+bb[0],0.f), fmaxf(acc[i][1]+bb[1],0.f),
                 fmaxf(acc[i][2]+bb[2],0.f), fmaxf(acc[i][3]+bb[3],0.f)};
    float4 oB = {fmaxf(acc[i][4]+bb[4],0.f), fmaxf(acc[i][5]+bb[5],0.f),
                 fmaxf(acc[i][6]+bb[6],0.f), fmaxf(acc[i][7]+bb[7],0.f)};
    *(float4*)&hidl[r][cbase]   = oA;
    *(float4*)&hidl[r][cbase+4] = oB;
  }
  __syncthreads();
  float esum = 0.f;
  #pragma unroll
  for (int rep = 0; rep < 2; rep++) {
    int o = t + rep * 128;
    int nl = o >> 2, i = o & 3;
    float s = bp2[i];
    for (int k = 0; k < 128; k += 4) {
      float4 hv = *(const float4*)&hidl[nl][k];
      s = fmaf(hv.x, Wp2[(k+0)*4 + i],
          fmaf(hv.y, Wp2[(k+1)*4 + i],
          fmaf(hv.z, Wp2[(k+2)*4 + i],
          fmaf(hv.w, Wp2[(k+3)*4 + i], s))));
    }
    int n = r0 + nl;
    if (n < N_NODES) {
      float e = expf(s);
      elg[n*4 + i] = e;
      esum += e;
    }
  }
  #pragma unroll
  for (int msk = 1; msk < 64; msk <<= 1) esum += __shfl_xor(esum, msk);
  if ((t & 63) == 0) wred[t >> 6] = esum;
  __syncthreads();
  if (t == 0) atomicAdd(tot, wred[0] + wred[1]);
}

// ---------------- normalize: out = elg * (1/tot) ----------------------------
__global__ void __launch_bounds__(1024) k_sm_final(const float* __restrict__ elg,
                                                   const float* __restrict__ tot,
                                                   float* __restrict__ out) {
  int i = blockIdx.x * 1024 + threadIdx.x;
  float inv = 1.f / tot[0];
  if (i < N_NODES * 4) out[i] = elg[i] * inv;
}

extern "C" void kernel_launch(void* const* d_in, const int* in_sizes, int n_in,
                              void* d_out, int out_size, void* d_ws, size_t ws_size,
                              hipStream_t stream) {
  const float* x    = (const float*)d_in[0];
  const int*   ei   = (const int*)  d_in[1];
  const float* ea   = (const float*)d_in[2];
  const float* Wl1  = (const float*)d_in[3];
  const float* bl1  = (const float*)d_in[4];
  const float* Wr1  = (const float*)d_in[5];
  const float* br1  = (const float*)d_in[6];
  const float* We1  = (const float*)d_in[7];
  const float* att1 = (const float*)d_in[8];
  const float* bias1= (const float*)d_in[9];
  const float* g1   = (const float*)d_in[10];
  const float* be1  = (const float*)d_in[11];
  const float* Wl2  = (const float*)d_in[12];
  const float* bl2  = (const float*)d_in[13];
  const float* Wr2  = (const float*)d_in[14];
  const float* br2  = (const float*)d_in[15];
  const float* We2  = (const float*)d_in[16];
  const float* att2 = (const float*)d_in[17];
  const float* bias2= (const float*)d_in[18];
  const float* g2   = (const float*)d_in[19];
  const float* be2  = (const float*)d_in[20];
  const float* Wp1  = (const float*)d_in[21];
  const float* bp1  = (const float*)d_in[22];
  const float* Wp2  = (const float*)d_in[23];
  const float* bp2  = (const float*)d_in[24];
  float* out = (float*)d_out;

  const int* srcp = ei;
  const int* dstp = ei + N_EDGES;

  // workspace layout: [deg | cursor | asum | tot] zeroed in ONE memset
  int*   deg    = (int*)d_ws;               // 10240
  int*   cursor = deg + 10240;              // 10240
  float* asum   = (float*)(cursor + 10240); // 10240
  float* tot    = asum + 10240;             // 16
  int*   offs   = (int*)(tot + 16);         // 10240
  float* lattr  = (float*)(offs + 10240);   // 10240
  int2*  cpk    = (int2*)(lattr + 10240);   // N_AUG (+pad) int2
  float* h1     = (float*)(cpk + 330752);   // 2560000
  float* xl2    = h1 + 2560000;             // 2560000
  float* xr2    = xl2 + 2560000;            // 2560000
  float* elg    = xr2 + 2560000;            // 40960
  float* h2     = h1;                       // h1 dead after gemm

  hipMemsetAsync(deg, 0, (3 * 10240 + 16) * sizeof(int), stream);

  k_deg    <<<(N_EDGES + 255)/256, 256, 0, stream>>>(dstp, ea, deg, asum);
  k_scan   <<<1, 256, 0, stream>>>(deg, asum, offs, lattr);
  k_scatter<<<(N_AUG + 255)/256, 256, 0, stream>>>(srcp, dstp, ea, lattr, offs,
                                                   cursor, cpk);
  k_conv1  <<<N_NODES/4, 256, 0, stream>>>(x, Wl1, bl1, Wr1, br1, We1, att1,
                                           offs, cpk, bias1, g1, be1, h1);
  k_gemm_dual<<<dim3(79, 4), 256, 0, stream>>>(h1, Wl2, bl2, Wr2, br2, xl2, xr2);
  k_conv2  <<<N_NODES/4, 256, 0, stream>>>(xl2, xr2, offs, cpk,
                                           We2, att2, bias2, g2, be2, h2);
  k_policy <<<157, 128, 0, stream>>>(h2, Wp1, bp1, Wp2, bp2, elg, tot);
  k_sm_final<<<40, 1024, 0, stream>>>(elg, tot, out);
}

// Round 7
// 363.058 us; speedup vs baseline: 1.0380x; 1.0380x over previous
//
#include <hip/hip_runtime.h>
#include <math.h>

#define N_NODES 10000
#define N_EDGES 320000
#define N_AUG   (N_EDGES + N_NODES)
#define HID     256

// bf16 round-to-nearest-even, as the low 16 bits of a uint
static __device__ __forceinline__ unsigned bf16rne(float f) {
  unsigned u = __float_as_uint(f);
  return (u + 0x7FFFu + ((u >> 16) & 1u)) >> 16;
}

// ---------------- degree + edge_attr segment sum ----------------
__global__ void k_deg(const int* __restrict__ dst, const float* __restrict__ ea,
                      int* __restrict__ deg, float* __restrict__ asum) {
  int e = blockIdx.x * blockDim.x + threadIdx.x;
  if (e < N_EDGES) {
    int d = dst[e];
    atomicAdd(&deg[d], 1);
    atomicAdd(&asum[d], ea[e]);
  }
}

// ------- exclusive scan of (deg+1) over 10000 nodes (parallel), + loop_attr --
__global__ void __launch_bounds__(256) k_scan(
    const int* __restrict__ deg, const float* __restrict__ asum,
    int* __restrict__ offs, float* __restrict__ lattr) {
  __shared__ int wsum[4];
  int t = threadIdx.x;
  int base = t * 40;
  int s = 0;
  for (int i = 0; i < 40; i++) {
    int n = base + i;
    if (n < N_NODES) s += deg[n] + 1;
  }
  int v = s;
  #pragma unroll
  for (int d = 1; d < 64; d <<= 1) {
    int u = __shfl_up(v, d);
    if ((t & 63) >= d) v += u;
  }
  if ((t & 63) == 63) wsum[t >> 6] = v;
  __syncthreads();
  int wb = 0;
  for (int i = 0; i < (t >> 6); i++) wb += wsum[i];
  int run = wb + v - s;
  for (int i = 0; i < 40; i++) {
    int n = base + i;
    if (n < N_NODES) {
      offs[n] = run;
      int d = deg[n];
      run += d + 1;
      lattr[n] = asum[n] / (float)max(d, 1);
    }
  }
  if (t == 255) offs[N_NODES] = wb + v;
}

// ------- scatter edges (incl. self loops) into CSR by dst, packed (src,ea) --
__global__ void k_scatter(const int* __restrict__ src, const int* __restrict__ dst,
                          const float* __restrict__ ea, const float* __restrict__ lattr,
                          const int* __restrict__ offs, int* __restrict__ cursor,
                          int2* __restrict__ cpk) {
  int e = blockIdx.x * blockDim.x + threadIdx.x;
  if (e >= N_AUG) return;
  int s, d; float a;
  if (e < N_EDGES) { s = src[e]; d = dst[e]; a = ea[e]; }
  else             { s = e - N_EDGES; d = s; a = lattr[s]; }
  int pos = offs[d] + atomicAdd(&cursor[d], 1);
  cpk[pos] = make_int2(s, __float_as_int(a));
}

// ---------------- conv1: fully fused, vector broadcast loads, 4-edge unroll -
#define C1_EDGE(xs, av, l0, l1, l2, l3, p)                                              \
  {                                                                                     \
    l0 = fmaf(xs.x,wl0.x, fmaf(xs.y,wl1.x, fmaf(xs.z,wl2.x, fmaf(xs.w,wl3.x, blv.x)))); \
    l1 = fmaf(xs.x,wl0.y, fmaf(xs.y,wl1.y, fmaf(xs.z,wl2.y, fmaf(xs.w,wl3.y, blv.y)))); \
    l2 = fmaf(xs.x,wl0.z, fmaf(xs.y,wl1.z, fmaf(xs.z,wl2.z, fmaf(xs.w,wl3.z, blv.z)))); \
    l3 = fmaf(xs.x,wl0.w, fmaf(xs.y,wl1.w, fmaf(xs.z,wl2.w, fmaf(xs.w,wl3.w, blv.w)))); \
    float m0 = l0 + fmaf(av, we.x, r4.x); m0 = fmaxf(m0, 0.2f*m0);                      \
    float m1 = l1 + fmaf(av, we.y, r4.y); m1 = fmaxf(m1, 0.2f*m1);                      \
    float m2 = l2 + fmaf(av, we.z, r4.z); m2 = fmaxf(m2, 0.2f*m2);                      \
    float m3 = l3 + fmaf(av, we.w, r4.w); m3 = fmaxf(m3, 0.2f*m3);                      \
    p = m0*at.x + m1*at.y + m2*at.z + m3*at.w;                                          \
  }

__global__ void __launch_bounds__(256) k_conv1(
    const float* __restrict__ x,
    const float* __restrict__ Wl, const float* __restrict__ bl,
    const float* __restrict__ Wr, const float* __restrict__ br,
    const float* __restrict__ We, const float* __restrict__ att,
    const int* __restrict__ offs, const int2* __restrict__ cpk,
    const float* __restrict__ bias, const float* __restrict__ g,
    const float* __restrict__ be, float* __restrict__ hout) {
  int t = threadIdx.x;
  int n = blockIdx.x * 4 + (t >> 6);
  int c = 4 * (t & 63);

  float4 wl0 = *(const float4*)&Wl[0*HID + c];
  float4 wl1 = *(const float4*)&Wl[1*HID + c];
  float4 wl2 = *(const float4*)&Wl[2*HID + c];
  float4 wl3 = *(const float4*)&Wl[3*HID + c];
  float4 blv = *(const float4*)&bl[c];
  float4 we  = *(const float4*)&We[c];
  float4 at  = *(const float4*)&att[c];

  float4 xn = *(const float4*)&x[n*4];
  float4 r4;
  {
    float4 wr0 = *(const float4*)&Wr[0*HID + c];
    float4 wr1 = *(const float4*)&Wr[1*HID + c];
    float4 wr2 = *(const float4*)&Wr[2*HID + c];
    float4 wr3 = *(const float4*)&Wr[3*HID + c];
    float4 brv = *(const float4*)&br[c];
    r4.x = fmaf(xn.x,wr0.x, fmaf(xn.y,wr1.x, fmaf(xn.z,wr2.x, fmaf(xn.w,wr3.x, brv.x))));
    r4.y = fmaf(xn.x,wr0.y, fmaf(xn.y,wr1.y, fmaf(xn.z,wr2.y, fmaf(xn.w,wr3.y, brv.y))));
    r4.z = fmaf(xn.x,wr0.z, fmaf(xn.y,wr1.z, fmaf(xn.z,wr2.z, fmaf(xn.w,wr3.z, brv.z))));
    r4.w = fmaf(xn.x,wr0.w, fmaf(xn.y,wr1.w, fmaf(xn.z,wr2.w, fmaf(xn.w,wr3.w, brv.w))));
  }

  int js = __builtin_amdgcn_readfirstlane(offs[n]);
  int je = __builtin_amdgcn_readfirstlane(offs[n+1]);

  float D = 0.f, a0 = 0.f, a1 = 0.f, a2 = 0.f, a3 = 0.f;

  int j = js;
  for (; j + 3 < je; j += 4) {
    int2 eA = cpk[j], eB = cpk[j+1], eC = cpk[j+2], eD = cpk[j+3];
    float4 xA = *(const float4*)&x[eA.x*4];   // broadcast vector load
    float4 xB = *(const float4*)&x[eB.x*4];
    float4 xC = *(const float4*)&x[eC.x*4];
    float4 xD = *(const float4*)&x[eD.x*4];
    float avA = __int_as_float(eA.y), avB = __int_as_float(eB.y);
    float avC = __int_as_float(eC.y), avD = __int_as_float(eD.y);

    float lA0,lA1,lA2,lA3,pA, lB0,lB1,lB2,lB3,pB;
    float lC0,lC1,lC2,lC3,pC, lD0,lD1,lD2,lD3,pD;
    C1_EDGE(xA, avA, lA0,lA1,lA2,lA3, pA);
    C1_EDGE(xB, avB, lB0,lB1,lB2,lB3, pB);
    C1_EDGE(xC, avC, lC0,lC1,lC2,lC3, pC);
    C1_EDGE(xD, avD, lD0,lD1,lD2,lD3, pD);

    #pragma unroll
    for (int msk = 1; msk < 16; msk <<= 1) {
      pA += __shfl_xor(pA, msk);
      pB += __shfl_xor(pB, msk);
      pC += __shfl_xor(pC, msk);
      pD += __shfl_xor(pD, msk);
    }
    float eAx = expf(pA), eBx = expf(pB), eCx = expf(pC), eDx = expf(pD);
    D += (eAx + eBx) + (eCx + eDx);
    a0 = fmaf(eDx, lD0, fmaf(eCx, lC0, fmaf(eBx, lB0, fmaf(eAx, lA0, a0))));
    a1 = fmaf(eDx, lD1, fmaf(eCx, lC1, fmaf(eBx, lB1, fmaf(eAx, lA1, a1))));
    a2 = fmaf(eDx, lD2, fmaf(eCx, lC2, fmaf(eBx, lB2, fmaf(eAx, lA2, a2))));
    a3 = fmaf(eDx, lD3, fmaf(eCx, lC3, fmaf(eBx, lB3, fmaf(eAx, lA3, a3))));
  }
  for (; j < je; j++) {
    int2 eA = cpk[j];
    float4 xA = *(const float4*)&x[eA.x*4];
    float avA = __int_as_float(eA.y);
    float lA0,lA1,lA2,lA3,pA;
    C1_EDGE(xA, avA, lA0,lA1,lA2,lA3, pA);
    #pragma unroll
    for (int msk = 1; msk < 16; msk <<= 1) pA += __shfl_xor(pA, msk);
    float eAx = expf(pA);
    D += eAx;
    a0 = fmaf(eAx, lA0, a0);
    a1 = fmaf(eAx, lA1, a1);
    a2 = fmaf(eAx, lA2, a2);
    a3 = fmaf(eAx, lA3, a3);
  }

  float inv = 1.f / D;
  float4 b4 = *(const float4*)&bias[c];
  float o0 = fmaf(a0, inv, b4.x);
  float o1 = fmaf(a1, inv, b4.y);
  float o2 = fmaf(a2, inv, b4.z);
  float o3 = fmaf(a3, inv, b4.w);

  float s = o0 + o1 + o2 + o3;
  #pragma unroll
  for (int msk = 1; msk < 64; msk <<= 1) s += __shfl_xor(s, msk);
  float mu = s * (1.f / 256.f);
  float d0 = o0 - mu, d1 = o1 - mu, d2 = o2 - mu, d3 = o3 - mu;
  float sq = d0*d0 + d1*d1 + d2*d2 + d3*d3;
  #pragma unroll
  for (int msk = 1; msk < 64; msk <<= 1) sq += __shfl_xor(sq, msk);
  float rstd = rsqrtf(sq * (1.f / 256.f) + 1e-5f);
  float4 g4  = *(const float4*)&g[c];
  float4 be4 = *(const float4*)&be[c];
  float4 o;
  o.x = fmaxf(fmaf(d0 * rstd, g4.x, be4.x), 0.f);
  o.y = fmaxf(fmaf(d1 * rstd, g4.y, be4.y), 0.f);
  o.z = fmaxf(fmaf(d2 * rstd, g4.z, be4.z), 0.f);
  o.w = fmaxf(fmaf(d3 * rstd, g4.w, be4.w), 0.f);
  *(float4*)&hout[n*HID + c] = o;
}

// ---------------- conv2: bf16-packed gather, no online max, 8-edge unroll ---
#define C2_LOAD(q, xs)                                  \
  float4 xs;                                            \
  xs.x = __uint_as_float(q.x << 16);                    \
  xs.y = __uint_as_float(q.x & 0xFFFF0000u);            \
  xs.z = __uint_as_float(q.y << 16);                    \
  xs.w = __uint_as_float(q.y & 0xFFFF0000u);

#define C2_EDGE(xs, av, p)                                        \
  {                                                               \
    float m0 = xs.x + fmaf(av, we.x, r4.x); m0 = fmaxf(m0, 0.2f*m0); \
    float m1 = xs.y + fmaf(av, we.y, r4.y); m1 = fmaxf(m1, 0.2f*m1); \
    float m2 = xs.z + fmaf(av, we.z, r4.z); m2 = fmaxf(m2, 0.2f*m2); \
    float m3 = xs.w + fmaf(av, we.w, r4.w); m3 = fmaxf(m3, 0.2f*m3); \
    p = m0*at.x + m1*at.y + m2*at.z + m3*at.w;                    \
  }

__global__ void __launch_bounds__(256) k_conv2(
    const uint2* __restrict__ xlb, const float* __restrict__ xr,
    const int* __restrict__ offs, const int2* __restrict__ cpk,
    const float* __restrict__ We, const float* __restrict__ att,
    const float* __restrict__ bias, const float* __restrict__ g,
    const float* __restrict__ be, float* __restrict__ hout) {
  int t = threadIdx.x;
  int n = blockIdx.x * 4 + (t >> 6);
  int lane = t & 63;
  int c = 4 * lane;
  float4 r4 = *(const float4*)&xr[n*HID + c];
  float4 we = *(const float4*)&We[c];
  float4 at = *(const float4*)&att[c];
  int js = __builtin_amdgcn_readfirstlane(offs[n]);
  int je = __builtin_amdgcn_readfirstlane(offs[n+1]);

  float D = 0.f, a0 = 0.f, a1 = 0.f, a2 = 0.f, a3 = 0.f;

  int j = js;
  for (; j + 7 < je; j += 8) {
    int2 e0 = cpk[j],   e1 = cpk[j+1], e2 = cpk[j+2], e3 = cpk[j+3];
    int2 e4 = cpk[j+4], e5 = cpk[j+5], e6 = cpk[j+6], e7 = cpk[j+7];
    uint2 q0 = xlb[e0.x*64 + lane];
    uint2 q1 = xlb[e1.x*64 + lane];
    uint2 q2 = xlb[e2.x*64 + lane];
    uint2 q3 = xlb[e3.x*64 + lane];
    uint2 q4 = xlb[e4.x*64 + lane];
    uint2 q5 = xlb[e5.x*64 + lane];
    uint2 q6 = xlb[e6.x*64 + lane];
    uint2 q7 = xlb[e7.x*64 + lane];
    C2_LOAD(q0, xs0); C2_LOAD(q1, xs1); C2_LOAD(q2, xs2); C2_LOAD(q3, xs3);
    C2_LOAD(q4, xs4); C2_LOAD(q5, xs5); C2_LOAD(q6, xs6); C2_LOAD(q7, xs7);
    float av0 = __int_as_float(e0.y), av1 = __int_as_float(e1.y);
    float av2 = __int_as_float(e2.y), av3 = __int_as_float(e3.y);
    float av4 = __int_as_float(e4.y), av5 = __int_as_float(e5.y);
    float av6 = __int_as_float(e6.y), av7 = __int_as_float(e7.y);

    float p0,p1,p2,p3,p4,p5,p6,p7;
    C2_EDGE(xs0, av0, p0); C2_EDGE(xs1, av1, p1);
    C2_EDGE(xs2, av2, p2); C2_EDGE(xs3, av3, p3);
    C2_EDGE(xs4, av4, p4); C2_EDGE(xs5, av5, p5);
    C2_EDGE(xs6, av6, p6); C2_EDGE(xs7, av7, p7);
    #pragma unroll
    for (int msk = 1; msk < 64; msk <<= 1) {
      p0 += __shfl_xor(p0, msk); p1 += __shfl_xor(p1, msk);
      p2 += __shfl_xor(p2, msk); p3 += __shfl_xor(p3, msk);
      p4 += __shfl_xor(p4, msk); p5 += __shfl_xor(p5, msk);
      p6 += __shfl_xor(p6, msk); p7 += __shfl_xor(p7, msk);
    }
    float x0 = expf(p0), x1 = expf(p1), x2 = expf(p2), x3 = expf(p3);
    float x4 = expf(p4), x5 = expf(p5), x6 = expf(p6), x7 = expf(p7);
    D += ((x0 + x1) + (x2 + x3)) + ((x4 + x5) + (x6 + x7));
    a0 = fmaf(x3, xs3.x, fmaf(x2, xs2.x, fmaf(x1, xs1.x, fmaf(x0, xs0.x, a0))));
    a0 = fmaf(x7, xs7.x, fmaf(x6, xs6.x, fmaf(x5, xs5.x, fmaf(x4, xs4.x, a0))));
    a1 = fmaf(x3, xs3.y, fmaf(x2, xs2.y, fmaf(x1, xs1.y, fmaf(x0, xs0.y, a1))));
    a1 = fmaf(x7, xs7.y, fmaf(x6, xs6.y, fmaf(x5, xs5.y, fmaf(x4, xs4.y, a1))));
    a2 = fmaf(x3, xs3.z, fmaf(x2, xs2.z, fmaf(x1, xs1.z, fmaf(x0, xs0.z, a2))));
    a2 = fmaf(x7, xs7.z, fmaf(x6, xs6.z, fmaf(x5, xs5.z, fmaf(x4, xs4.z, a2))));
    a3 = fmaf(x3, xs3.w, fmaf(x2, xs2.w, fmaf(x1, xs1.w, fmaf(x0, xs0.w, a3))));
    a3 = fmaf(x7, xs7.w, fmaf(x6, xs6.w, fmaf(x5, xs5.w, fmaf(x4, xs4.w, a3))));
  }
  for (; j < je; j++) {
    int2 e0 = cpk[j];
    float av0 = __int_as_float(e0.y);
    uint2 q0 = xlb[e0.x*64 + lane];
    C2_LOAD(q0, xs0);
    float p0;
    C2_EDGE(xs0, av0, p0);
    #pragma unroll
    for (int msk = 1; msk < 64; msk <<= 1) p0 += __shfl_xor(p0, msk);
    float x0 = expf(p0);
    D += x0;
    a0 = fmaf(x0, xs0.x, a0);
    a1 = fmaf(x0, xs0.y, a1);
    a2 = fmaf(x0, xs0.z, a2);
    a3 = fmaf(x0, xs0.w, a3);
  }

  float inv = 1.f / D;
  float4 b4 = *(const float4*)&bias[c];
  float o0 = fmaf(a0, inv, b4.x);
  float o1 = fmaf(a1, inv, b4.y);
  float o2 = fmaf(a2, inv, b4.z);
  float o3 = fmaf(a3, inv, b4.w);

  float s = o0 + o1 + o2 + o3;
  #pragma unroll
  for (int msk = 1; msk < 64; msk <<= 1) s += __shfl_xor(s, msk);
  float mu = s * (1.f / 256.f);
  float d0 = o0 - mu, d1 = o1 - mu, d2 = o2 - mu, d3 = o3 - mu;
  float sq = d0*d0 + d1*d1 + d2*d2 + d3*d3;
  #pragma unroll
  for (int msk = 1; msk < 64; msk <<= 1) sq += __shfl_xor(sq, msk);
  float rstd = rsqrtf(sq * (1.f / 256.f) + 1e-5f);
  float4 g4  = *(const float4*)&g[c];
  float4 be4 = *(const float4*)&be[c];
  float4 o;
  o.x = fmaxf(fmaf(d0 * rstd, g4.x, be4.x), 0.f);
  o.y = fmaxf(fmaf(d1 * rstd, g4.y, be4.y), 0.f);
  o.z = fmaxf(fmaf(d2 * rstd, g4.z, be4.z), 0.f);
  o.w = fmaxf(fmaf(d3 * rstd, g4.w, be4.w), 0.f);
  *(float4*)&hout[n*HID + c] = o;
}

// ---------------- dual GEMM: 64x64 tile x2 outputs, 4x4/thread (R4 config) --
// grid (157,4) = 628 blocks x 4 waves = 2512 waves (~30% occ). LDS padded to
// 68 (write scatter 2-way max = free). O1 packed to bf16 pairs for conv2.
__global__ void __launch_bounds__(256) k_gemm_dual(
    const float* __restrict__ A,
    const float* __restrict__ W1, const float* __restrict__ b1,
    const float* __restrict__ W2, const float* __restrict__ b2,
    uint2* __restrict__ O1b, float* __restrict__ O2) {
  __shared__ __align__(16) float As[16][68];
  __shared__ __align__(16) float Ws1[16][68];
  __shared__ __align__(16) float Ws2[16][68];
  int t = threadIdx.x;
  int r0 = blockIdx.x * 64;
  int c0 = blockIdx.y * 64;
  int tx = t & 15, ty = t >> 4;

  float acc1[4][4] = {{0}};
  float acc2[4][4] = {{0}};

  int ar = t >> 2;                 // 0..63 row in tile
  int ak = (t & 3) * 4;            // 0..12 k in block
  int arow = min(r0 + ar, N_NODES - 1);
  int wk = t >> 4;                 // 0..15
  int wc = (t & 15) * 4;           // 0..60

  for (int k0 = 0; k0 < HID; k0 += 16) {
    float4 av  = *(const float4*)&A [arow*HID + k0 + ak];
    float4 w1v = *(const float4*)&W1[(k0+wk)*HID + c0 + wc];
    float4 w2v = *(const float4*)&W2[(k0+wk)*HID + c0 + wc];
    __syncthreads();
    As[ak+0][ar] = av.x; As[ak+1][ar] = av.y;
    As[ak+2][ar] = av.z; As[ak+3][ar] = av.w;
    *(float4*)&Ws1[wk][wc] = w1v;
    *(float4*)&Ws2[wk][wc] = w2v;
    __syncthreads();
    #pragma unroll
    for (int k = 0; k < 16; k++) {
      float4 a4  = *(const float4*)&As [k][4*ty];
      float4 w14 = *(const float4*)&Ws1[k][4*tx];
      float4 w24 = *(const float4*)&Ws2[k][4*tx];
      const float aa[4]  = {a4.x, a4.y, a4.z, a4.w};
      const float ww1[4] = {w14.x, w14.y, w14.z, w14.w};
      const float ww2[4] = {w24.x, w24.y, w24.z, w24.w};
      #pragma unroll
      for (int i = 0; i < 4; i++)
        #pragma unroll
        for (int jj = 0; jj < 4; jj++) {
          acc1[i][jj] = fmaf(aa[i], ww1[jj], acc1[i][jj]);
          acc2[i][jj] = fmaf(aa[i], ww2[jj], acc2[i][jj]);
        }
    }
  }
  int cb = c0 + 4*tx;
  float4 b1v = *(const float4*)&b1[cb];
  float4 b2v = *(const float4*)&b2[cb];
  #pragma unroll
  for (int i = 0; i < 4; i++) {
    int r = r0 + 4*ty + i;
    if (r < N_NODES) {
      float o10 = acc1[i][0]+b1v.x, o11 = acc1[i][1]+b1v.y;
      float o12 = acc1[i][2]+b1v.z, o13 = acc1[i][3]+b1v.w;
      uint2 pk;
      pk.x = bf16rne(o10) | (bf16rne(o11) << 16);
      pk.y = bf16rne(o12) | (bf16rne(o13) << 16);
      O1b[r*64 + (cb >> 2)] = pk;
      float4 o2 = {acc2[i][0]+b2v.x, acc2[i][1]+b2v.y, acc2[i][2]+b2v.z, acc2[i][3]+b2v.w};
      *(float4*)&O2[r*HID + cb] = o2;
    }
  }
}

// ------- fused policy head: 64x128 tile, 8x8/thread, then 128-dot + exp -----
__global__ void __launch_bounds__(128) k_policy(
    const float* __restrict__ h,
    const float* __restrict__ Wp1, const float* __restrict__ bp1,
    const float* __restrict__ Wp2, const float* __restrict__ bp2,
    float* __restrict__ elg, float* __restrict__ tot) {
  __shared__ __align__(16) float As[16][68];
  __shared__ __align__(16) float Ws[16][132];
  __shared__ __align__(16) float hidl[64][132];
  __shared__ float wred[2];
  int t = threadIdx.x;
  int r0 = blockIdx.x * 64;
  int tx = t & 15, ty = t >> 4;

  float acc[8][8] = {{0}};

  int ar  = t >> 1;
  int akh = (t & 1) * 8;
  int arow = min(r0 + ar, N_NODES - 1);
  int wk = t >> 3;
  int wc = (t & 7) * 16;

  for (int k0 = 0; k0 < HID; k0 += 16) {
    const float* Ap = &h[arow*HID + k0 + akh];
    float4 av0 = *(const float4*)&Ap[0];
    float4 av1 = *(const float4*)&Ap[4];
    const float* Wp = &Wp1[(k0+wk)*128 + wc];
    float4 wv0 = *(const float4*)&Wp[0];
    float4 wv1 = *(const float4*)&Wp[4];
    float4 wv2 = *(const float4*)&Wp[8];
    float4 wv3 = *(const float4*)&Wp[12];
    __syncthreads();
    As[akh+0][ar]=av0.x; As[akh+1][ar]=av0.y; As[akh+2][ar]=av0.z; As[akh+3][ar]=av0.w;
    As[akh+4][ar]=av1.x; As[akh+5][ar]=av1.y; As[akh+6][ar]=av1.z; As[akh+7][ar]=av1.w;
    *(float4*)&Ws[wk][wc+ 0] = wv0;
    *(float4*)&Ws[wk][wc+ 4] = wv1;
    *(float4*)&Ws[wk][wc+ 8] = wv2;
    *(float4*)&Ws[wk][wc+12] = wv3;
    __syncthreads();
    #pragma unroll
    for (int k = 0; k < 16; k++) {
      float4 aA = *(const float4*)&As[k][ty*8];
      float4 aB = *(const float4*)&As[k][ty*8+4];
      float4 wA = *(const float4*)&Ws[k][tx*8];
      float4 wB = *(const float4*)&Ws[k][tx*8+4];
      const float aa[8] = {aA.x,aA.y,aA.z,aA.w, aB.x,aB.y,aB.z,aB.w};
      const float ww[8] = {wA.x,wA.y,wA.z,wA.w, wB.x,wB.y,wB.z,wB.w};
      #pragma unroll
      for (int i = 0; i < 8; i++)
        #pragma unroll
        for (int jj = 0; jj < 8; jj++)
          acc[i][jj] = fmaf(aa[i], ww[jj], acc[i][jj]);
    }
  }
  int cbase = tx*8;
  float4 bA = *(const float4*)&bp1[cbase];
  float4 bB = *(const float4*)&bp1[cbase+4];
  const float bb[8] = {bA.x,bA.y,bA.z,bA.w, bB.x,bB.y,bB.z,bB.w};
  #pragma unroll
  for (int i = 0; i < 8; i++) {
    int r = ty*8 + i;
    float4 oA = {fmaxf(acc[i][0]+bb[0],0.f), fmaxf(acc[i][1]+bb[1],0.f),
                 fmaxf(acc[i][2]+bb[2],0.f), fmaxf(acc[i][3]+bb[3],0.f)};
    float4 oB = {fmaxf(acc[i][4]+bb[4],0.f), fmaxf(acc[i][5]+bb[5],0.f),
                 fmaxf(acc[i][6]+bb[6],0.f), fmaxf(acc[i][7]+bb[7],0.f)};
    *(float4*)&hidl[r][cbase]   = oA;
    *(float4*)&hidl[r][cbase+4] = oB;
  }
  __syncthreads();
  float esum = 0.f;
  #pragma unroll
  for (int rep = 0; rep < 2; rep++) {
    int o = t + rep * 128;
    int nl = o >> 2, i = o & 3;
    float s = bp2[i];
    for (int k = 0; k < 128; k += 4) {
      float4 hv = *(const float4*)&hidl[nl][k];
      s = fmaf(hv.x, Wp2[(k+0)*4 + i],
          fmaf(hv.y, Wp2[(k+1)*4 + i],
          fmaf(hv.z, Wp2[(k+2)*4 + i],
          fmaf(hv.w, Wp2[(k+3)*4 + i], s))));
    }
    int n = r0 + nl;
    if (n < N_NODES) {
      float e = expf(s);
      elg[n*4 + i] = e;
      esum += e;
    }
  }
  #pragma unroll
  for (int msk = 1; msk < 64; msk <<= 1) esum += __shfl_xor(esum, msk);
  if ((t & 63) == 0) wred[t >> 6] = esum;
  __syncthreads();
  if (t == 0) atomicAdd(tot, wred[0] + wred[1]);
}

// ---------------- normalize: out = elg * (1/tot) ----------------------------
__global__ void __launch_bounds__(1024) k_sm_final(const float* __restrict__ elg,
                                                   const float* __restrict__ tot,
                                                   float* __restrict__ out) {
  int i = blockIdx.x * 1024 + threadIdx.x;
  float inv = 1.f / tot[0];
  if (i < N_NODES * 4) out[i] = elg[i] * inv;
}

extern "C" void kernel_launch(void* const* d_in, const int* in_sizes, int n_in,
                              void* d_out, int out_size, void* d_ws, size_t ws_size,
                              hipStream_t stream) {
  const float* x    = (const float*)d_in[0];
  const int*   ei   = (const int*)  d_in[1];
  const float* ea   = (const float*)d_in[2];
  const float* Wl1  = (const float*)d_in[3];
  const float* bl1  = (const float*)d_in[4];
  const float* Wr1  = (const float*)d_in[5];
  const float* br1  = (const float*)d_in[6];
  const float* We1  = (const float*)d_in[7];
  const float* att1 = (const float*)d_in[8];
  const float* bias1= (const float*)d_in[9];
  const float* g1   = (const float*)d_in[10];
  const float* be1  = (const float*)d_in[11];
  const float* Wl2  = (const float*)d_in[12];
  const float* bl2  = (const float*)d_in[13];
  const float* Wr2  = (const float*)d_in[14];
  const float* br2  = (const float*)d_in[15];
  const float* We2  = (const float*)d_in[16];
  const float* att2 = (const float*)d_in[17];
  const float* bias2= (const float*)d_in[18];
  const float* g2   = (const float*)d_in[19];
  const float* be2  = (const float*)d_in[20];
  const float* Wp1  = (const float*)d_in[21];
  const float* bp1  = (const float*)d_in[22];
  const float* Wp2  = (const float*)d_in[23];
  const float* bp2  = (const float*)d_in[24];
  float* out = (float*)d_out;

  const int* srcp = ei;
  const int* dstp = ei + N_EDGES;

  // workspace layout: [deg | cursor | asum | tot] zeroed in ONE memset
  int*   deg    = (int*)d_ws;               // 10240
  int*   cursor = deg + 10240;              // 10240
  float* asum   = (float*)(cursor + 10240); // 10240
  float* tot    = asum + 10240;             // 16
  int*   offs   = (int*)(tot + 16);         // 10240
  float* lattr  = (float*)(offs + 10240);   // 10240
  int2*  cpk    = (int2*)(lattr + 10240);   // N_AUG (+pad) int2
  float* h1     = (float*)(cpk + 330752);   // 2560000 floats
  uint2* xl2b   = (uint2*)(h1 + 2560000);   // 640000 uint2 (bf16-packed xl2)
  float* xr2    = (float*)(xl2b + 640000);  // 2560000 floats
  float* elg    = xr2 + 2560000;            // 40960
  float* h2     = h1;                       // h1 dead after gemm

  hipMemsetAsync(deg, 0, (3 * 10240 + 16) * sizeof(int), stream);

  k_deg    <<<(N_EDGES + 255)/256, 256, 0, stream>>>(dstp, ea, deg, asum);
  k_scan   <<<1, 256, 0, stream>>>(deg, asum, offs, lattr);
  k_scatter<<<(N_AUG + 255)/256, 256, 0, stream>>>(srcp, dstp, ea, lattr, offs,
                                                   cursor, cpk);
  k_conv1  <<<N_NODES/4, 256, 0, stream>>>(x, Wl1, bl1, Wr1, br1, We1, att1,
                                           offs, cpk, bias1, g1, be1, h1);
  k_gemm_dual<<<dim3(157, 4), 256, 0, stream>>>(h1, Wl2, bl2, Wr2, br2, xl2b, xr2);
  k_conv2  <<<N_NODES/4, 256, 0, stream>>>(xl2b, xr2, offs, cpk,
                                           We2, att2, bias2, g2, be2, h2);
  k_policy <<<157, 128, 0, stream>>>(h2, Wp1, bp1, Wp2, bp2, elg, tot);
  k_sm_final<<<40, 1024, 0, stream>>>(elg, tot, out);
}